// Round 1
// baseline (16546.796 us; speedup 1.0000x reference)
//
#include <hip/hip_runtime.h>
#include <cmath>

// ---------------- problem constants ----------------
#define HID   896
#define HALFD 448
#define BINSD 256
#define BB    16
#define SS    2048
#define NWG   56          // 56 hidden-tiles of 16 (56*16 = 896)

typedef _Float16 half8  __attribute__((ext_vector_type(8)));
typedef float    f32x4v __attribute__((ext_vector_type(4)));
typedef float    f32x2v __attribute__((ext_vector_type(2)));

static __device__ __forceinline__ f32x4v mfma16(half8 a, half8 b, f32x4v c) {
    return __builtin_amdgcn_mfma_f32_16x16x32_f16(a, b, c, 0, 0, 0);
}

// ---------------- workspace layout (bytes, 256-aligned) ----------------
// W_hh f16 [2688][896]
#define OFF_WHH16 0UL
// Wc1^T f16 [448][448], Wf1^T, Wc2^T [256][448], Wf2^T [256][448]
#define OFF_WC1T  4816896UL
#define OFF_WF1T  5218304UL
#define OFF_WC2T  5619712UL
#define OFF_WF2T  5849088UL
// h double buffer f16 [2][16][896]
#define OFF_HBUF  6078464UL
// hidden_coarse f16 [32768][448]
#define OFF_HC    6135808UL
// per-step barrier counters u32 [2049]
#define OFF_CNT   35495936UL

// ============================================================
// Kernel 1: convert weights fp32 -> f16 (W_hh direct; head weights transposed
// so the MFMA B-operand (fixed n, contiguous k) is a contiguous 16B load)
// ============================================================
__global__ void wrnn_conv(const float* __restrict__ Whh,
                          const float* __restrict__ Wc1, const float* __restrict__ Wc2,
                          const float* __restrict__ Wf1, const float* __restrict__ Wf2,
                          _Float16* __restrict__ Whh16,
                          _Float16* __restrict__ Wc1T, _Float16* __restrict__ Wc2T,
                          _Float16* __restrict__ Wf1T, _Float16* __restrict__ Wf2T)
{
    const int tid    = blockIdx.x * blockDim.x + threadIdx.x;
    const int stride = gridDim.x * blockDim.x;
    for (int i = tid; i < 2688 * 896; i += stride) Whh16[i] = (_Float16)Whh[i];
    for (int i = tid; i < 448 * 448; i += stride) {
        int n = i / 448, k = i % 448;
        Wc1T[i] = (_Float16)Wc1[k * 448 + n];
        Wf1T[i] = (_Float16)Wf1[k * 448 + n];
    }
    for (int i = tid; i < 256 * 448; i += stride) {
        int n = i / 448, k = i % 448;
        Wc2T[i] = (_Float16)Wc2[k * 256 + n];
        Wf2T[i] = (_Float16)Wf2[k * 256 + n];
    }
}

// ============================================================
// Kernel 2: fused projections + GRU scan.
// 56 WGs x 192 threads (3 waves). WG w owns hidden dims [16w,16w+16).
// Wave g in {0,1,2} owns gate g: its 16x896 slice of W_hh lives in VGPRs
// for the whole scan. Batch (16) is the MFMA N dim.
// Cross-WG per-step sync: cnt[t] counters (release add / acquire spin),
// h exchanged via agent-scope f16 double buffer.
// ============================================================
__global__ __launch_bounds__(192, 1) void wrnn_scan(
    const float* __restrict__ cond,   // [16][2048][3][896]
    const float* __restrict__ sig,    // [16][2048][2]
    const float* __restrict__ tcg,    // [16][2048]
    const float* __restrict__ Wc,     // [2][1344]
    const float* __restrict__ Wf,     // [3][1344]
    const float* __restrict__ bih,    // [2688]
    const float* __restrict__ bhh,    // [2688]
    const _Float16* __restrict__ Whh16, // [2688][896]
    _Float16* __restrict__ hbuf,      // [2][16][896]
    _Float16* __restrict__ hc,        // [32768][448]
    unsigned int* __restrict__ cnt)   // [2049]
{
    const int w  = blockIdx.x;        // hidden tile
    const int g  = threadIdx.x >> 6;  // gate = wave id (0:r 1:z 2:n)
    const int l  = threadIdx.x & 63;
    const int b  = l & 15;            // batch (MFMA col / n)
    const int lg = l >> 4;            // lane group 0..3
    const int ibase = w * 16;
    const int i0 = ibase + lg * 4;    // + q gives this lane's C rows

    // ---- persistent A fragments: W_hh rows [g*896+ibase .. +16), all K ----
    half8 A[28];
    {
        const _Float16* ap = Whh16 + (size_t)(g * HID + ibase + b) * HID + lg * 8;
        #pragma unroll
        for (int f = 0; f < 28; ++f) A[f] = *(const half8*)(ap + f * 32);
    }

    // ---- per-lane constants: projection coefficients and biases ----
    float pc0[4], pc1[4], pc2[4], bi4[4], bh4[4];
    #pragma unroll
    for (int q = 0; q < 4; ++q) {
        int i = i0 + q;
        int j = g * HID + i;
        bi4[q] = bih[j];
        bh4[q] = bhh[j];              // g<2: folded into pre-act; g==2: bhn
        if (i < HALFD) {              // coarse half: proj from input_signal @ W_c
            int col = g * HALFD + i;
            pc0[q] = Wc[col]; pc1[q] = Wc[1344 + col]; pc2[q] = 0.f;
        } else {                      // fine half: proj from [sig, tc] @ W_f
            int col = g * HALFD + (i - HALFD);
            pc0[q] = Wf[col]; pc1[q] = Wf[1344 + col]; pc2[q] = Wf[2688 + col];
        }
    }

    float hold[4] = {0.f, 0.f, 0.f, 0.f};   // fp32 recurrent state (wave 0)
    float r4[4];
    __shared__ float lds_z[256], lds_nm[256], lds_xn[256];
    const int idx = (lg * 4) * 16 + b;      // + q*16

    for (int t = 0; t < SS; ++t) {
        // ---- issue h-independent loads first (overlap with barrier wait) ----
        f32x4v cond4 = *(const f32x4v*)(cond + (((size_t)b * SS + t) * 3 + g) * HID + i0);
        f32x2v s01   = *(const f32x2v*)(sig + ((size_t)b * SS + t) * 2);
        float  tcv   = tcg[(size_t)b * SS + t];

        // ---- wait until h_t fully published (t=0: h=0, skip) ----
        if (t > 0) {
            if (threadIdx.x == 0) {
                while (__hip_atomic_load(cnt + t, __ATOMIC_RELAXED, __HIP_MEMORY_SCOPE_AGENT) < NWG) { }
                (void)__hip_atomic_load(cnt + t, __ATOMIC_ACQUIRE, __HIP_MEMORY_SCOPE_AGENT);
            }
            __syncthreads();
        }

        // ---- y = W_slice @ h_t  (skip at t=0: h0 = 0) ----
        f32x4v ac0 = {0,0,0,0}, ac1 = {0,0,0,0}, ac2 = {0,0,0,0}, ac3 = {0,0,0,0};
        if (t > 0) {
            const _Float16* hb = hbuf + (size_t)(t & 1) * (BB * HID) + b * HID + lg * 8;
            half8 Bf[28];
            #pragma unroll
            for (int f = 0; f < 28; ++f) Bf[f] = *(const half8*)(hb + f * 32);
            #pragma unroll
            for (int f = 0; f < 28; f += 4) {
                ac0 = mfma16(A[f + 0], Bf[f + 0], ac0);
                ac1 = mfma16(A[f + 1], Bf[f + 1], ac1);
                ac2 = mfma16(A[f + 2], Bf[f + 2], ac2);
                ac3 = mfma16(A[f + 3], Bf[f + 3], ac3);
            }
        }
        f32x4v acc = (ac0 + ac1) + (ac2 + ac3);

        // ---- gate pre-activations; exchange via LDS ----
        float proj[4];
        #pragma unroll
        for (int q = 0; q < 4; ++q) proj[q] = pc0[q] * s01[0] + pc1[q] * s01[1] + pc2[q] * tcv;

        if (g == 0) {
            #pragma unroll
            for (int q = 0; q < 4; ++q) {
                float pre = acc[q] + cond4[q] + proj[q] + bi4[q] + bh4[q];
                r4[q] = 1.f / (1.f + expf(-pre));
            }
        } else if (g == 1) {
            #pragma unroll
            for (int q = 0; q < 4; ++q) {
                float pre = acc[q] + cond4[q] + proj[q] + bi4[q] + bh4[q];
                lds_z[idx + q * 16] = 1.f / (1.f + expf(-pre));
            }
        } else {
            #pragma unroll
            for (int q = 0; q < 4; ++q) {
                lds_nm[idx + q * 16] = acc[q] + bh4[q];              // Wn h + bhn
                lds_xn[idx + q * 16] = cond4[q] + proj[q] + bi4[q];  // x_n
            }
        }
        __syncthreads();

        // ---- combine (wave 0), publish h_{t+1}, signal ----
        if (g == 0) {
            union { _Float16 h[4]; unsigned long long u; } pk;
            #pragma unroll
            for (int q = 0; q < 4; ++q) {
                float z  = lds_z[idx + q * 16];
                float nm = lds_nm[idx + q * 16];
                float xn = lds_xn[idx + q * 16];
                float n  = tanhf(xn + r4[q] * nm);
                float h  = (1.f - z) * n + z * hold[q];
                hold[q] = h;
                pk.h[q] = (_Float16)h;
            }
            size_t hoff = (size_t)((t + 1) & 1) * (BB * HID) + (size_t)b * HID + ibase + lg * 4;
            __hip_atomic_store((unsigned long long*)(hbuf + hoff), pk.u,
                               __ATOMIC_RELAXED, __HIP_MEMORY_SCOPE_AGENT);
            if (threadIdx.x == 0)
                __hip_atomic_fetch_add(cnt + t + 1, 1u, __ATOMIC_RELEASE, __HIP_MEMORY_SCOPE_AGENT);
            if (w < 28)  // hidden_coarse slice (off critical path, plain store)
                *(unsigned long long*)(hc + ((size_t)b * SS + t) * HALFD + ibase + lg * 4) = pk.u;
        }
    }
}

// ============================================================
// Kernel 3: output heads. grid 1024 = 512 row-tiles x 2 paths.
// out = relu(HC(64x448) @ W1 + b1) @ W2 + b2, intermediate in padded LDS.
// ============================================================
__global__ __launch_bounds__(256, 2) void wrnn_head(
    const _Float16* __restrict__ hc,
    const _Float16* __restrict__ W1Tc, const _Float16* __restrict__ W1Tf,
    const _Float16* __restrict__ W2Tc, const _Float16* __restrict__ W2Tf,
    const float* __restrict__ b1c, const float* __restrict__ b1f,
    const float* __restrict__ b2c, const float* __restrict__ b2f,
    float* __restrict__ out)
{
    const int path = blockIdx.x & 1;
    const int rt   = blockIdx.x >> 1;        // 0..511
    const int wm   = threadIdx.x >> 6;       // wave = m-tile
    const int l    = threadIdx.x & 63;
    const int ln   = l & 15, lg = l >> 4;
    const int rowbase = rt * 64;

    const _Float16* W1T = path ? W1Tf : W1Tc;
    const _Float16* W2T = path ? W2Tf : W2Tc;
    const float* b1 = path ? b1f : b1c;
    const float* b2 = path ? b2f : b2c;

    __shared__ _Float16 T[64 * 456];         // +8 f16 pad: breaks 896B-stride bank conflict

    // ---- stage 1: C1(64x448) = HC @ W1 ----
    f32x4v acc[28];
    #pragma unroll
    for (int nt = 0; nt < 28; ++nt) acc[nt] = f32x4v{0,0,0,0};
    const _Float16* ab = hc + (size_t)(rowbase + wm * 16 + ln) * HALFD + lg * 8;
    for (int f = 0; f < 14; ++f) {
        half8 a = *(const half8*)(ab + f * 32);
        #pragma unroll
        for (int nt = 0; nt < 28; ++nt) {
            half8 bb = *(const half8*)(W1T + (size_t)(nt * 16 + ln) * HALFD + f * 32 + lg * 8);
            acc[nt] = mfma16(a, bb, acc[nt]);
        }
    }
    #pragma unroll
    for (int nt = 0; nt < 28; ++nt) {
        float bias = b1[nt * 16 + ln];
        #pragma unroll
        for (int q = 0; q < 4; ++q) {
            float v = acc[nt][q] + bias;
            v = fmaxf(v, 0.f);
            T[(wm * 16 + lg * 4 + q) * 456 + nt * 16 + ln] = (_Float16)v;
        }
    }
    __syncthreads();

    // ---- stage 2: out(64x256) = T @ W2 ----
    f32x4v a2[16];
    #pragma unroll
    for (int nt = 0; nt < 16; ++nt) a2[nt] = f32x4v{0,0,0,0};
    for (int f = 0; f < 14; ++f) {
        half8 a = *(const half8*)(&T[(wm * 16 + ln) * 456 + f * 32 + lg * 8]);
        #pragma unroll
        for (int nt = 0; nt < 16; ++nt) {
            half8 bb = *(const half8*)(W2T + (size_t)(nt * 16 + ln) * HALFD + f * 32 + lg * 8);
            a2[nt] = mfma16(a, bb, a2[nt]);
        }
    }
    #pragma unroll
    for (int nt = 0; nt < 16; ++nt) {
        float bias = b2[nt * 16 + ln];
        #pragma unroll
        for (int q = 0; q < 4; ++q) {
            size_t row = (size_t)rowbase + wm * 16 + lg * 4 + q;
            out[(size_t)path * (32768UL * 256UL) + row * 256 + nt * 16 + ln] = a2[nt][q] + bias;
        }
    }
}

// ============================================================
extern "C" void kernel_launch(void* const* d_in, const int* in_sizes, int n_in,
                              void* d_out, int out_size, void* d_ws, size_t ws_size,
                              hipStream_t stream)
{
    (void)in_sizes; (void)n_in; (void)out_size; (void)ws_size;
    const float* cond = (const float*)d_in[0];
    const float* sig  = (const float*)d_in[1];
    const float* tcg  = (const float*)d_in[2];
    const float* Wc   = (const float*)d_in[3];
    const float* Wf   = (const float*)d_in[4];
    const float* Whh  = (const float*)d_in[5];
    const float* bih  = (const float*)d_in[6];
    const float* bhh  = (const float*)d_in[7];
    const float* Wc1  = (const float*)d_in[8];
    const float* bc1  = (const float*)d_in[9];
    const float* Wc2  = (const float*)d_in[10];
    const float* bc2  = (const float*)d_in[11];
    const float* Wf1  = (const float*)d_in[12];
    const float* bf1  = (const float*)d_in[13];
    const float* Wf2  = (const float*)d_in[14];
    const float* bf2  = (const float*)d_in[15];

    char* ws = (char*)d_ws;
    _Float16* Whh16 = (_Float16*)(ws + OFF_WHH16);
    _Float16* Wc1T  = (_Float16*)(ws + OFF_WC1T);
    _Float16* Wf1T  = (_Float16*)(ws + OFF_WF1T);
    _Float16* Wc2T  = (_Float16*)(ws + OFF_WC2T);
    _Float16* Wf2T  = (_Float16*)(ws + OFF_WF2T);
    _Float16* hbuf  = (_Float16*)(ws + OFF_HBUF);
    _Float16* hc    = (_Float16*)(ws + OFF_HC);
    unsigned int* cnt = (unsigned int*)(ws + OFF_CNT);

    hipMemsetAsync(cnt, 0, 2049 * sizeof(unsigned int), stream);

    wrnn_conv<<<1024, 256, 0, stream>>>(Whh, Wc1, Wc2, Wf1, Wf2,
                                        Whh16, Wc1T, Wc2T, Wf1T, Wf2T);

    wrnn_scan<<<NWG, 192, 0, stream>>>(cond, sig, tcg, Wc, Wf, bih, bhh,
                                       Whh16, hbuf, hc, cnt);

    wrnn_head<<<1024, 256, 0, stream>>>(hc, Wc1T, Wf1T, Wc2T, Wf2T,
                                        bc1, bf1, bc2, bf2, (float*)d_out);
}

// Round 2
// 15025.014 us; speedup vs baseline: 1.1013x; 1.1013x over previous
//
#include <hip/hip_runtime.h>
#include <cmath>

// ---------------- problem constants ----------------
#define HID   896
#define HALFD 448
#define BINSD 256
#define BB    16
#define SS    2048
#define NWG   28          // 28 WGs x 32 hidden dims each

typedef _Float16 half8  __attribute__((ext_vector_type(8)));
typedef float    f32x4v __attribute__((ext_vector_type(4)));

static __device__ __forceinline__ f32x4v mfma16(half8 a, half8 b, f32x4v c) {
    return __builtin_amdgcn_mfma_f32_16x16x32_f16(a, b, c, 0, 0, 0);
}

// Coherent (device-scope) 16B load: bypasses L1/L2, reads at the MALL.
static __device__ __forceinline__ half8 gload16_coh(const _Float16* p) {
    half8 r;
    asm volatile("global_load_dwordx4 %0, %1, off sc0 sc1" : "=v"(r) : "v"(p));
    return r;
}
// Normal cached 16B load issued early via asm so it can't be sunk past the
// vmcnt(0) that follows the B-fragment loads.
static __device__ __forceinline__ f32x4v gload16_f32(const float* p) {
    f32x4v r;
    asm volatile("global_load_dwordx4 %0, %1, off" : "=v"(r) : "v"(p));
    return r;
}

// ---------------- workspace layout (bytes) ----------------
#define OFF_WHH16 0UL          // W_hh f16 [2688][896]
#define OFF_WC1T  4816896UL    // head weights, transposed f16
#define OFF_WF1T  5218304UL
#define OFF_WC2T  5619712UL
#define OFF_WF2T  5849088UL
#define OFF_HBUF  6078464UL    // h double buffer f16 [2][16][896]
#define OFF_HC    6135808UL    // hidden_coarse f16 [32768][448]
#define OFF_FLAG  35495936UL   // per-WG progress flags u32 [28]

// ============================================================
// Kernel 1: convert weights fp32 -> f16
// ============================================================
__global__ void wrnn_conv(const float* __restrict__ Whh,
                          const float* __restrict__ Wc1, const float* __restrict__ Wc2,
                          const float* __restrict__ Wf1, const float* __restrict__ Wf2,
                          _Float16* __restrict__ Whh16,
                          _Float16* __restrict__ Wc1T, _Float16* __restrict__ Wc2T,
                          _Float16* __restrict__ Wf1T, _Float16* __restrict__ Wf2T)
{
    const int tid    = blockIdx.x * blockDim.x + threadIdx.x;
    const int stride = gridDim.x * blockDim.x;
    for (int i = tid; i < 2688 * 896; i += stride) Whh16[i] = (_Float16)Whh[i];
    for (int i = tid; i < 448 * 448; i += stride) {
        int n = i / 448, k = i % 448;
        Wc1T[i] = (_Float16)Wc1[k * 448 + n];
        Wf1T[i] = (_Float16)Wf1[k * 448 + n];
    }
    for (int i = tid; i < 256 * 448; i += stride) {
        int n = i / 448, k = i % 448;
        Wc2T[i] = (_Float16)Wc2[k * 256 + n];
        Wf2T[i] = (_Float16)Wf2[k * 256 + n];
    }
}

// ============================================================
// Kernel 2: fused projections + GRU scan.
// 28 WGs x 192 threads (3 waves). WG w owns hidden dims [32w, 32w+32).
// Wave g owns gate g for BOTH 16-row tiles: A = 2x28 half8 = 224 VGPR,
// pinned in registers via empty "+v" asm (blocks rematerialization).
// Cross-WG sync: per-WG flag words, sc1 (MALL-coherent) data path only —
// no acquire/release fences, no buffer_inv/wbl2, no atomic RMW contention.
// ============================================================
__global__ __launch_bounds__(192, 1) void wrnn_scan(
    const float* __restrict__ cond,   // [16][2048][3][896]
    const float* __restrict__ sig,    // [16][2048][2]
    const float* __restrict__ tcg,    // [16][2048]
    const float* __restrict__ Wc,     // [2][1344]
    const float* __restrict__ Wf,     // [3][1344]
    const float* __restrict__ bih,    // [2688]
    const float* __restrict__ bhh,    // [2688]
    const _Float16* __restrict__ Whh16, // [2688][896]
    _Float16* __restrict__ hbuf,      // [2][16][896]
    _Float16* __restrict__ hc,        // [32768][448]
    unsigned int* __restrict__ flag)  // [28]
{
    const int w  = blockIdx.x;
    const int g  = threadIdx.x >> 6;  // gate = wave (0:r 1:z 2:n)
    const int l  = threadIdx.x & 63;
    const int b  = l & 15;            // batch (MFMA col)
    const int lg = l >> 4;
    const int dbase = w * 32;

    // ---- persistent A fragments: rows [g*896+dbase .. +32), all K ----
    half8 A0[28], A1[28];
    {
        const _Float16* ap = Whh16 + (size_t)(g * HID + dbase + b) * HID + lg * 8;
        #pragma unroll
        for (int f = 0; f < 28; ++f) {
            A0[f] = *(const half8*)(ap + f * 32);
            A1[f] = *(const half8*)(ap + (size_t)16 * HID + f * 32);
        }
    }

    // ---- per-lane constants for the 8 owned outputs (tile*4 + q) ----
    float pc0[8], pc1[8], pc2[8], bi8[8], bh8[8];
    #pragma unroll
    for (int e = 0; e < 8; ++e) {
        int i = dbase + (e >> 2) * 16 + lg * 4 + (e & 3);
        int j = g * HID + i;
        bi8[e] = bih[j]; bh8[e] = bhh[j];
        if (i < HALFD) { int col = g * HALFD + i;
            pc0[e] = Wc[col]; pc1[e] = Wc[1344 + col]; pc2[e] = 0.f; }
        else { int col = g * HALFD + (i - HALFD);
            pc0[e] = Wf[col]; pc1[e] = Wf[1344 + col]; pc2[e] = Wf[2688 + col]; }
    }

    __shared__ float lds_z[512], lds_nm[512], lds_xn[512];
    const int x0 = lg * 4 * 16 + b;   // + (e&3)*16 + (e>>2)*256

    float hold[8] = {0,0,0,0,0,0,0,0};
    float r8[8];

    const float* cp0 = cond + ((size_t)b * SS * 3 + g) * HID + dbase + lg * 4;
    const float* cp1 = cp0 + 16;
    const float* sp  = sig + (size_t)b * SS * 2;
    const float* tp  = tcg + (size_t)b * SS;
    _Float16*       pub = hbuf + (size_t)b * HID + dbase + lg * 4;
    _Float16*       hcp = hc   + (size_t)b * SS * HALFD + dbase + lg * 4;
    const _Float16* hrd = hbuf + (size_t)b * HID + lg * 8;

    for (int t = 0; t < SS; ++t) {
        // pin A in VGPRs (defeats per-iteration reload/remat)
        #pragma unroll
        for (int f = 0; f < 28; ++f) {
            asm volatile("" : "+v"(A0[f]));
            asm volatile("" : "+v"(A1[f]));
        }

        // h-independent loads, issued first (cached path)
        f32x4v cv0 = gload16_f32(cp0);
        f32x4v cv1 = gload16_f32(cp1);
        float s0 = sp[2 * t], s1 = sp[2 * t + 1], tc = tp[t];

        // ---- y = W_slice @ h_t (skip t=0: h0=0) ----
        f32x4v acc0 = {0,0,0,0}, acc1 = {0,0,0,0};
        if (t > 0) {
            const _Float16* hb = hrd + (size_t)(t & 1) * (BB * HID);
            half8 Bf[28];
            #pragma unroll
            for (int f = 0; f < 28; ++f) Bf[f] = gload16_coh(hb + f * 32);
            asm volatile("s_waitcnt vmcnt(0)" ::: "memory");
            __builtin_amdgcn_sched_barrier(0);
            #pragma unroll
            for (int f = 0; f < 28; ++f) {
                acc0 = mfma16(A0[f], Bf[f], acc0);   // B shared by both tiles
                acc1 = mfma16(A1[f], Bf[f], acc1);
            }
        } else {
            asm volatile("s_waitcnt vmcnt(0)" ::: "memory");
            __builtin_amdgcn_sched_barrier(0);
        }

        // ---- gate pre-activations ----
        float accv[8] = {acc0[0],acc0[1],acc0[2],acc0[3],
                         acc1[0],acc1[1],acc1[2],acc1[3]};
        float cvv[8]  = {cv0[0],cv0[1],cv0[2],cv0[3],
                         cv1[0],cv1[1],cv1[2],cv1[3]};
        if (g == 0) {
            #pragma unroll
            for (int e = 0; e < 8; ++e) {
                float pre = accv[e] + cvv[e] + pc0[e]*s0 + pc1[e]*s1 + pc2[e]*tc + bi8[e] + bh8[e];
                r8[e] = 1.f / (1.f + expf(-pre));
            }
        } else if (g == 1) {
            #pragma unroll
            for (int e = 0; e < 8; ++e) {
                float pre = accv[e] + cvv[e] + pc0[e]*s0 + pc1[e]*s1 + pc2[e]*tc + bi8[e] + bh8[e];
                lds_z[(e >> 2) * 256 + x0 + (e & 3) * 16] = 1.f / (1.f + expf(-pre));
            }
        } else {
            #pragma unroll
            for (int e = 0; e < 8; ++e) {
                lds_nm[(e >> 2) * 256 + x0 + (e & 3) * 16] = accv[e] + bh8[e];
                lds_xn[(e >> 2) * 256 + x0 + (e & 3) * 16] =
                    cvv[e] + pc0[e]*s0 + pc1[e]*s1 + pc2[e]*tc + bi8[e];
            }
        }
        __syncthreads();

        // ---- combine (wave 0), publish h_{t+1}, signal, poll ----
        if (g == 0) {
            union { _Float16 h[4]; unsigned long long u; } p0, p1;
            #pragma unroll
            for (int e = 0; e < 8; ++e) {
                int idx = (e >> 2) * 256 + x0 + (e & 3) * 16;
                float z  = lds_z[idx];
                float nn = tanhf(lds_xn[idx] + r8[e] * lds_nm[idx]);
                float h  = (1.f - z) * nn + z * hold[e];
                hold[e] = h;
                if (e < 4) p0.h[e] = (_Float16)h; else p1.h[e - 4] = (_Float16)h;
            }
            _Float16* pb = pub + (size_t)((t + 1) & 1) * (BB * HID);
            __hip_atomic_store((unsigned long long*)pb,        p0.u,
                               __ATOMIC_RELAXED, __HIP_MEMORY_SCOPE_AGENT);
            __hip_atomic_store((unsigned long long*)(pb + 16), p1.u,
                               __ATOMIC_RELAXED, __HIP_MEMORY_SCOPE_AGENT);
            if (w < 14) {   // coarse half -> hc (plain; kernel-end flush suffices)
                *(unsigned long long*)(hcp)      = p0.u;
                *(unsigned long long*)(hcp + 16) = p1.u;
            }
            asm volatile("s_waitcnt vmcnt(0)" ::: "memory");  // h at MALL
            if (l == 0)
                __hip_atomic_store(flag + w, (unsigned int)(t + 1),
                                   __ATOMIC_RELAXED, __HIP_MEMORY_SCOPE_AGENT);
            // poll all 28 flags with one wave-wide load per iteration
            const unsigned int* fp = flag + (l < NWG ? l : 0);
            const unsigned need = (unsigned)(t + 1);
            while (1) {
                unsigned v = __hip_atomic_load(fp, __ATOMIC_RELAXED,
                                               __HIP_MEMORY_SCOPE_AGENT);
                if (__all((int)(v >= need))) break;
            }
        }
        __syncthreads();

        cp0 += 3 * HID; cp1 += 3 * HID; hcp += HALFD;
    }
}

// ============================================================
// Kernel 3: output heads. grid 1024 = 512 row-tiles x 2 paths.
// ============================================================
__global__ __launch_bounds__(256, 2) void wrnn_head(
    const _Float16* __restrict__ hc,
    const _Float16* __restrict__ W1Tc, const _Float16* __restrict__ W1Tf,
    const _Float16* __restrict__ W2Tc, const _Float16* __restrict__ W2Tf,
    const float* __restrict__ b1c, const float* __restrict__ b1f,
    const float* __restrict__ b2c, const float* __restrict__ b2f,
    float* __restrict__ out)
{
    const int path = blockIdx.x & 1;
    const int rt   = blockIdx.x >> 1;
    const int wm   = threadIdx.x >> 6;
    const int l    = threadIdx.x & 63;
    const int ln   = l & 15, lg = l >> 4;
    const int rowbase = rt * 64;

    const _Float16* W1T = path ? W1Tf : W1Tc;
    const _Float16* W2T = path ? W2Tf : W2Tc;
    const float* b1 = path ? b1f : b1c;
    const float* b2 = path ? b2f : b2c;

    __shared__ _Float16 T[64 * 456];

    f32x4v acc[28];
    #pragma unroll
    for (int nt = 0; nt < 28; ++nt) acc[nt] = f32x4v{0,0,0,0};
    const _Float16* ab = hc + (size_t)(rowbase + wm * 16 + ln) * HALFD + lg * 8;
    for (int f = 0; f < 14; ++f) {
        half8 a = *(const half8*)(ab + f * 32);
        #pragma unroll
        for (int nt = 0; nt < 28; ++nt) {
            half8 bb = *(const half8*)(W1T + (size_t)(nt * 16 + ln) * HALFD + f * 32 + lg * 8);
            acc[nt] = mfma16(a, bb, acc[nt]);
        }
    }
    #pragma unroll
    for (int nt = 0; nt < 28; ++nt) {
        float bias = b1[nt * 16 + ln];
        #pragma unroll
        for (int q = 0; q < 4; ++q) {
            float v = fmaxf(acc[nt][q] + bias, 0.f);
            T[(wm * 16 + lg * 4 + q) * 456 + nt * 16 + ln] = (_Float16)v;
        }
    }
    __syncthreads();

    f32x4v a2[16];
    #pragma unroll
    for (int nt = 0; nt < 16; ++nt) a2[nt] = f32x4v{0,0,0,0};
    for (int f = 0; f < 14; ++f) {
        half8 a = *(const half8*)(&T[(wm * 16 + ln) * 456 + f * 32 + lg * 8]);
        #pragma unroll
        for (int nt = 0; nt < 16; ++nt) {
            half8 bb = *(const half8*)(W2T + (size_t)(nt * 16 + ln) * HALFD + f * 32 + lg * 8);
            a2[nt] = mfma16(a, bb, a2[nt]);
        }
    }
    #pragma unroll
    for (int nt = 0; nt < 16; ++nt) {
        float bias = b2[nt * 16 + ln];
        #pragma unroll
        for (int q = 0; q < 4; ++q) {
            size_t row = (size_t)rowbase + wm * 16 + lg * 4 + q;
            out[(size_t)path * (32768UL * 256UL) + row * 256 + nt * 16 + ln] = a2[nt][q] + bias;
        }
    }
}

// ============================================================
extern "C" void kernel_launch(void* const* d_in, const int* in_sizes, int n_in,
                              void* d_out, int out_size, void* d_ws, size_t ws_size,
                              hipStream_t stream)
{
    (void)in_sizes; (void)n_in; (void)out_size; (void)ws_size;
    const float* cond = (const float*)d_in[0];
    const float* sig  = (const float*)d_in[1];
    const float* tcg  = (const float*)d_in[2];
    const float* Wc   = (const float*)d_in[3];
    const float* Wf   = (const float*)d_in[4];
    const float* Whh  = (const float*)d_in[5];
    const float* bih  = (const float*)d_in[6];
    const float* bhh  = (const float*)d_in[7];
    const float* Wc1  = (const float*)d_in[8];
    const float* bc1  = (const float*)d_in[9];
    const float* Wc2  = (const float*)d_in[10];
    const float* bc2  = (const float*)d_in[11];
    const float* Wf1  = (const float*)d_in[12];
    const float* bf1  = (const float*)d_in[13];
    const float* Wf2  = (const float*)d_in[14];
    const float* bf2  = (const float*)d_in[15];

    char* ws = (char*)d_ws;
    _Float16* Whh16 = (_Float16*)(ws + OFF_WHH16);
    _Float16* Wc1T  = (_Float16*)(ws + OFF_WC1T);
    _Float16* Wf1T  = (_Float16*)(ws + OFF_WF1T);
    _Float16* Wc2T  = (_Float16*)(ws + OFF_WC2T);
    _Float16* Wf2T  = (_Float16*)(ws + OFF_WF2T);
    _Float16* hbuf  = (_Float16*)(ws + OFF_HBUF);
    _Float16* hc    = (_Float16*)(ws + OFF_HC);
    unsigned int* flag = (unsigned int*)(ws + OFF_FLAG);

    hipMemsetAsync(flag, 0, NWG * sizeof(unsigned int), stream);

    wrnn_conv<<<1024, 256, 0, stream>>>(Whh, Wc1, Wc2, Wf1, Wf2,
                                        Whh16, Wc1T, Wc2T, Wf1T, Wf2T);

    wrnn_scan<<<NWG, 192, 0, stream>>>(cond, sig, tcg, Wc, Wf, bih, bhh,
                                       Whh16, hbuf, hc, flag);

    wrnn_head<<<1024, 256, 0, stream>>>(hc, Wc1T, Wf1T, Wc2T, Wf2T,
                                        bc1, bf1, bc2, bf2, (float*)d_out);
}